// Round 1
// baseline (111.525 us; speedup 1.0000x reference)
//
#include <hip/hip_runtime.h>
#include <math.h>

#define B_ 1024
#define I_ 256
#define N_ 1024
#define O_ 256
#define EPSV 1e-5f

typedef unsigned short u16;
typedef short bf16x8 __attribute__((ext_vector_type(8)));   // 8 bf16 = 4 VGPRs
typedef float f32x4 __attribute__((ext_vector_type(4)));
typedef int i32x4 __attribute__((ext_vector_type(4)));

__device__ inline u16 f2bf(float f) {
    union { float f; unsigned int u; } v; v.f = f;
    unsigned int r = v.u + 0x7FFFu + ((v.u >> 16) & 1u);   // round-to-nearest-even
    return (u16)(r >> 16);
}

// Pack 8 fp32 -> 8 bf16 (RNE) via v_cvt_pk_bf16_f32: 4 instrs instead of ~32.
__device__ inline bf16x8 cvt8(const float4& a, const float4& b) {
    union { unsigned int u[4]; bf16x8 v; } r;
    asm("v_cvt_pk_bf16_f32 %0, %1, %2" : "=v"(r.u[0]) : "v"(a.x), "v"(a.y));
    asm("v_cvt_pk_bf16_f32 %0, %1, %2" : "=v"(r.u[1]) : "v"(a.z), "v"(a.w));
    asm("v_cvt_pk_bf16_f32 %0, %1, %2" : "=v"(r.u[2]) : "v"(b.x), "v"(b.y));
    asm("v_cvt_pk_bf16_f32 %0, %1, %2" : "=v"(r.u[3]) : "v"(b.z), "v"(b.w));
    return r.v;
}

__device__ inline float ssq8(const float4& a, const float4& b) {
    return a.x*a.x + a.y*a.y + a.z*a.z + a.w*a.w
         + b.x*b.x + b.y*b.y + b.z*b.z + b.w*b.w;
}

// Fragment-order storage: per (row16-tile, k32-tile) store 64 chunks of 8 bf16.
// chunk slot = quad*16 + (row&15) = lane; matches MFMA A/B layout
// (m|n = lane&15, k = (lane>>4)*8 + j). Tile = 512 u16 = 1 KB.

// ---------------------------------------------------------------------------
// Transpose + convert into fragment order (global dst) — used for W only now.
// ---------------------------------------------------------------------------
__device__ inline void transconv_frag(const float* __restrict__ in,
                                      u16* __restrict__ out, int R, int C,
                                      int r0, int c0, int t, float (*tile)[69]) {
    const int lr = t >> 2, lq = t & 3;
    #pragma unroll
    for (int j = 0; j < 4; ++j) {
        float4 v = *(const float4*)(in + (size_t)(r0 + lr) * C + c0 + lq * 16 + j * 4);
        *(float4*)&tile[lr][lq * 16 + j * 4] = v;
    }
    __syncthreads();
    const int oc = t >> 2, oq = t & 3;
    const int row = c0 + oc;
    const int ktiles = R >> 5;
    #pragma unroll
    for (int h = 0; h < 2; ++h) {
        const int k0 = r0 + oq * 16 + h * 8;
        const int kt = k0 >> 5, quad = (k0 >> 3) & 3;
        __align__(16) u16 tmp[8];
        #pragma unroll
        for (int e = 0; e < 8; ++e)
            tmp[e] = f2bf(tile[oq * 16 + h * 8 + e][oc]);
        const size_t off = ((size_t)((row >> 4) * ktiles + kt)) * 512
                         + (quad * 16 + (row & 15)) * 8;
        *(int4*)(out + off) = *(const int4*)tmp;
    }
}

// ---------------------------------------------------------------------------
// Fused prep + phi GEMM. Grid (17, 16, 2):
//   bx < 16:  phi block (64b x 64n tile, comp=z). Prologue transposes its
//             G[:, n0:n0+64] slice into LDS bf16 frags (+ gsq in LDS); K-loop
//             converts X fp32 -> A-frags inline (accumulating xsq in-register)
//             and reads B-frags from LDS. Epilogue -> frag-order P.
//   bx == 16: W [N][O] -> WT frag conversion (4 tiles per block).
// Eliminates the separate prep dispatch and all X/GT/xsq/gsq global arrays.
// ---------------------------------------------------------------------------
__global__ __launch_bounds__(256) void phi_fused(
    const float* __restrict__ x_re, const float* __restrict__ x_im,
    const float* __restrict__ G_re, const float* __restrict__ G_im,
    const float* __restrict__ W_re, const float* __restrict__ W_im,
    const float* __restrict__ s_re, const float* __restrict__ s_im,
    u16* __restrict__ WTfr, u16* __restrict__ WTfi,
    u16* __restrict__ Pfr, u16* __restrict__ Pfi)
{
    __shared__ union ShU {
        float tile[64][69];     // prologue staging (17.6 KB)
        u16 pbuf[8 * 512];      // epilogue P buffer (8 KB) — disjoint lifetime
    } sh;
    __shared__ u16 gfrag[4 * 8 * 512];   // 32 KB: [ntile(4)][ktile(8)][512]
    __shared__ float gsq_l[64];

    const int t = threadIdx.x;
    const int z = blockIdx.z;
    const int bx = blockIdx.x, by = blockIdx.y;

    if (bx == 16) {
        // ---- W conversion blocks: tile rt=by (N/64), ct=j (O/64) ----
        const float* Wsrc = z ? W_im : W_re;
        u16* Wdst = z ? WTfi : WTfr;
        #pragma unroll
        for (int j = 0; j < 4; ++j) {
            transconv_frag(Wsrc, Wdst, N_, O_, by * 64, j * 64, t, sh.tile);
            __syncthreads();
        }
        return;
    }

    const int n0 = bx * 64;
    const int m0 = by * 64;
    const float* Gsrc = z ? G_im : G_re;
    const float* Xsrc = z ? x_im : x_re;
    const float* s    = z ? s_im : s_re;
    u16* Pf = z ? Pfi : Pfr;

    // ---- Prologue: G[:, n0:n0+64) -> gfrag (LDS, frag order) + gsq ----
    const int lr = t >> 2, lq = t & 3;
    float4 ga[4][4];
    #pragma unroll
    for (int c = 0; c < 4; ++c)
        #pragma unroll
        for (int j = 0; j < 4; ++j)
            ga[c][j] = *(const float4*)(Gsrc + (size_t)(c * 64 + lr) * N_
                                        + n0 + lq * 16 + j * 4);
    float ssg = 0.f;
    #pragma unroll
    for (int c = 0; c < 4; ++c) {
        #pragma unroll
        for (int j = 0; j < 4; ++j)
            *(float4*)&sh.tile[lr][lq * 16 + j * 4] = ga[c][j];
        __syncthreads();
        #pragma unroll
        for (int h = 0; h < 2; ++h) {
            const int klo = lq * 16 + h * 8;               // 0..56
            const int kt = c * 2 + (klo >> 5);
            const int quad = (klo >> 3) & 3;
            __align__(16) u16 tmp[8];
            #pragma unroll
            for (int e = 0; e < 8; ++e) {
                const float g = sh.tile[klo + e][lr];
                ssg += g * g;
                tmp[e] = f2bf(g);
            }
            *(int4*)&gfrag[((lr >> 4) * 8 + kt) * 512 + (quad * 16 + (lr & 15)) * 8]
                = *(const int4*)tmp;
        }
        __syncthreads();
    }
    // lanes t = oc*4 + oq: reduce gsq over oq (low 2 lane bits)
    ssg += __shfl_xor(ssg, 1);
    ssg += __shfl_xor(ssg, 2);
    if (lq == 0) gsq_l[lr] = ssg;
    __syncthreads();

    // ---- K-loop: A from fp32 x (inline convert), B from LDS frags ----
    const int w = t >> 6, lane = t & 63;
    const int quad = lane >> 4, l16 = lane & 15;
    const int mw = (w >> 1) * 32, nw = (w & 1) * 32;
    const int ntl = nw >> 4;                                // 0 or 2

    const float* xr0 = Xsrc + (size_t)(m0 + mw + l16) * I_ + quad * 8;
    const float* xr1 = xr0 + (size_t)16 * I_;
    const u16* bp = gfrag + lane * 8;

    float4 cA00 = *(const float4*)(xr0);
    float4 cA01 = *(const float4*)(xr0 + 4);
    float4 cA10 = *(const float4*)(xr1);
    float4 cA11 = *(const float4*)(xr1 + 4);

    f32x4 acc[2][2] = {};
    float ss0 = 0.f, ss1 = 0.f;
    #pragma unroll
    for (int kt = 0; kt < 8; ++kt) {
        float4 nA00, nA01, nA10, nA11;
        if (kt < 7) {
            nA00 = *(const float4*)(xr0 + (kt + 1) * 32);
            nA01 = *(const float4*)(xr0 + (kt + 1) * 32 + 4);
            nA10 = *(const float4*)(xr1 + (kt + 1) * 32);
            nA11 = *(const float4*)(xr1 + (kt + 1) * 32 + 4);
        }
        bf16x8 fB0 = *(const bf16x8*)(bp + (size_t)((ntl    ) * 8 + kt) * 512);
        bf16x8 fB1 = *(const bf16x8*)(bp + (size_t)((ntl + 1) * 8 + kt) * 512);
        bf16x8 fA0 = cvt8(cA00, cA01);
        bf16x8 fA1 = cvt8(cA10, cA11);
        ss0 += ssq8(cA00, cA01);
        ss1 += ssq8(cA10, cA11);
        acc[0][0] = __builtin_amdgcn_mfma_f32_16x16x32_bf16(fA0, fB0, acc[0][0], 0, 0, 0);
        acc[0][1] = __builtin_amdgcn_mfma_f32_16x16x32_bf16(fA0, fB1, acc[0][1], 0, 0, 0);
        acc[1][0] = __builtin_amdgcn_mfma_f32_16x16x32_bf16(fA1, fB0, acc[1][0], 0, 0, 0);
        acc[1][1] = __builtin_amdgcn_mfma_f32_16x16x32_bf16(fA1, fB1, acc[1][1], 0, 0, 0);
        cA00 = nA00; cA01 = nA01; cA10 = nA10; cA11 = nA11;
    }
    // xsq[row]: lane l16 of tile mt holds sum over its 64 k-cols; reduce quads.
    ss0 += __shfl_xor(ss0, 16); ss0 += __shfl_xor(ss0, 32);
    ss1 += __shfl_xor(ss1, 16); ss1 += __shfl_xor(ss1, 32);

    // ---- Epilogue into LDS in fragment order. C/D: col=lane&15, row=quad*4+r.
    #pragma unroll
    for (int mt = 0; mt < 2; ++mt)
        #pragma unroll
        for (int nt = 0; nt < 2; ++nt) {
            const int col = nw + nt * 16 + l16;
            const int gn = n0 + col;
            const float gq = gsq_l[col];
            const float inv_s = 1.0f / fmaxf(s[gn], EPSV);
            #pragma unroll
            for (int r = 0; r < 4; ++r) {
                const int row = mw + mt * 16 + quad * 4 + r;
                const float xq = __shfl(mt ? ss1 : ss0, quad * 4 + r);
                const float v = xq - 2.0f * acc[mt][nt][r] + gq;
                const u16 p = f2bf(__expf(-v * inv_s));
                const int lt = (row >> 4) * 2 + (col >> 5);
                sh.pbuf[lt * 512 + (((col >> 3) & 3) * 16 + (row & 15)) * 8 + (col & 7)] = p;
            }
        }
    __syncthreads();

    const int lt2 = t >> 5, s32 = t & 31;
    const int mt_g = by * 4 + (lt2 >> 1);
    const int kt_g = bx * 2 + (lt2 & 1);
    const u16* src = sh.pbuf + lt2 * 512 + s32 * 16;
    u16* dst = Pf + (size_t)(mt_g * 32 + kt_g) * 512 + s32 * 16;
    *(int4*)dst = *(const int4*)src;
    *((int4*)dst + 1) = *((const int4*)src + 1);
}

// ---------------------------------------------------------------------------
// Complex GEMM, frag-direct, no atomics. Grid (8, 64) = 512 blocks
// (2 blocks/CU): each block 16(b) x 32(o); 4 waves each reduce a K-quarter
// (256) with 1x2 complex fragments + register prefetch; LDS cross-wave
// reduce + bias + coalesced float4 stores.
// ---------------------------------------------------------------------------
__global__ __launch_bounds__(256) void y_mfma(
    const u16* __restrict__ Pfr, const u16* __restrict__ Pfi,
    const u16* __restrict__ WTfr, const u16* __restrict__ WTfi,
    const float* __restrict__ b_re, const float* __restrict__ b_im,
    float* __restrict__ out)
{
    __shared__ float red[4][2][16][34];
    const int t = threadIdx.x;
    const int w = t >> 6, lane = t & 63;
    const int quad = lane >> 4, l16 = lane & 15;
    const int pm = blockIdx.y;        // P 16-row tile (32 ktiles)
    const int wo0 = blockIdx.x * 2;   // WT 16-row tiles

    const u16* Ar = Pfr + lane * 8;
    const u16* Ai = Pfi + lane * 8;
    const u16* Br = WTfr + lane * 8;
    const u16* Bi = WTfi + lane * 8;
    const size_t ao = (size_t)(pm * 32 + w * 8) * 512;
    const size_t b0o = (size_t)(wo0 * 32 + w * 8) * 512;
    const size_t b1o = (size_t)((wo0 + 1) * 32 + w * 8) * 512;

    bf16x8 cAr = *(const bf16x8*)(Ar + ao);
    bf16x8 cAi = *(const bf16x8*)(Ai + ao);
    bf16x8 cBr0 = *(const bf16x8*)(Br + b0o);
    bf16x8 cBi0 = *(const bf16x8*)(Bi + b0o);
    bf16x8 cBr1 = *(const bf16x8*)(Br + b1o);
    bf16x8 cBi1 = *(const bf16x8*)(Bi + b1o);

    f32x4 cr[2] = {}, ci[2] = {};
    #pragma unroll
    for (int ks = 0; ks < 8; ++ks) {
        bf16x8 nAr, nAi, nBr0, nBi0, nBr1, nBi1;
        if (ks < 7) {
            const size_t ko = (size_t)(ks + 1) * 512;
            nAr  = *(const bf16x8*)(Ar + ao + ko);
            nAi  = *(const bf16x8*)(Ai + ao + ko);
            nBr0 = *(const bf16x8*)(Br + b0o + ko);
            nBi0 = *(const bf16x8*)(Bi + b0o + ko);
            nBr1 = *(const bf16x8*)(Br + b1o + ko);
            nBi1 = *(const bf16x8*)(Bi + b1o + ko);
        }
        i32x4 tv = (*(const i32x4*)&cAi) ^ 0x80008000;   // negate bf16 pairs
        bf16x8 cAn = *(const bf16x8*)&tv;
        cr[0] = __builtin_amdgcn_mfma_f32_16x16x32_bf16(cAr, cBr0, cr[0], 0, 0, 0);
        cr[0] = __builtin_amdgcn_mfma_f32_16x16x32_bf16(cAn, cBi0, cr[0], 0, 0, 0);
        ci[0] = __builtin_amdgcn_mfma_f32_16x16x32_bf16(cAr, cBi0, ci[0], 0, 0, 0);
        ci[0] = __builtin_amdgcn_mfma_f32_16x16x32_bf16(cAi, cBr0, ci[0], 0, 0, 0);
        cr[1] = __builtin_amdgcn_mfma_f32_16x16x32_bf16(cAr, cBr1, cr[1], 0, 0, 0);
        cr[1] = __builtin_amdgcn_mfma_f32_16x16x32_bf16(cAn, cBi1, cr[1], 0, 0, 0);
        ci[1] = __builtin_amdgcn_mfma_f32_16x16x32_bf16(cAr, cBi1, ci[1], 0, 0, 0);
        ci[1] = __builtin_amdgcn_mfma_f32_16x16x32_bf16(cAi, cBr1, ci[1], 0, 0, 0);
        cAr = nAr; cAi = nAi;
        cBr0 = nBr0; cBi0 = nBi0; cBr1 = nBr1; cBi1 = nBi1;
    }

    // C/D: o_local = nt*16 + l16, b_local = quad*4 + r.
    #pragma unroll
    for (int nt = 0; nt < 2; ++nt) {
        const int o = nt * 16 + l16;
        #pragma unroll
        for (int r = 0; r < 4; ++r) {
            const int b = quad * 4 + r;
            red[w][0][b][o] = cr[nt][r];
            red[w][1][b][o] = ci[nt][r];
        }
    }
    __syncthreads();

    const int b = t >> 4, oq = t & 15;
    const int o = oq * 2;
    const int gb = blockIdx.y * 16 + b;
    const int go = blockIdx.x * 32 + o;
    float r0 = red[0][0][b][o]   + red[1][0][b][o]   + red[2][0][b][o]   + red[3][0][b][o];
    float i0 = red[0][1][b][o]   + red[1][1][b][o]   + red[2][1][b][o]   + red[3][1][b][o];
    float r1 = red[0][0][b][o+1] + red[1][0][b][o+1] + red[2][0][b][o+1] + red[3][0][b][o+1];
    float i1 = red[0][1][b][o+1] + red[1][1][b][o+1] + red[2][1][b][o+1] + red[3][1][b][o+1];
    float4 v;
    v.x = r0 + b_re[go];     v.y = i0 + b_im[go];
    v.z = r1 + b_re[go + 1]; v.w = i1 + b_im[go + 1];
    *(float4*)(out + ((size_t)gb * O_ + go) * 2) = v;
}

extern "C" void kernel_launch(void* const* d_in, const int* in_sizes, int n_in,
                              void* d_out, int out_size, void* d_ws, size_t ws_size,
                              hipStream_t stream) {
    const float* x_re = (const float*)d_in[0];
    const float* x_im = (const float*)d_in[1];
    const float* G_re = (const float*)d_in[2];
    const float* G_im = (const float*)d_in[3];
    const float* s_re = (const float*)d_in[4];
    const float* s_im = (const float*)d_in[5];
    const float* W_re = (const float*)d_in[6];
    const float* W_im = (const float*)d_in[7];
    const float* b_re = (const float*)d_in[8];
    const float* b_im = (const float*)d_in[9];
    float* out = (float*)d_out;

    u16* WTfr = (u16*)d_ws;
    u16* WTfi = WTfr + (size_t)O_ * N_;
    u16* Pfr  = WTfi + (size_t)O_ * N_;
    u16* Pfi  = Pfr  + (size_t)B_ * N_;

    phi_fused<<<dim3(17, 16, 2), 256, 0, stream>>>(
        x_re, x_im, G_re, G_im, W_re, W_im, s_re, s_im,
        WTfr, WTfi, Pfr, Pfi);

    y_mfma<<<dim3(O_ / 32, B_ / 16), 256, 0, stream>>>(
        Pfr, Pfi, WTfr, WTfi, b_re, b_im, out);
}

// Round 2
// 94.290 us; speedup vs baseline: 1.1828x; 1.1828x over previous
//
#include <hip/hip_runtime.h>
#include <math.h>

#define B_ 1024
#define I_ 256
#define N_ 1024
#define O_ 256
#define EPSV 1e-5f

typedef unsigned short u16;
typedef short bf16x8 __attribute__((ext_vector_type(8)));   // 8 bf16 = 4 VGPRs
typedef float f32x4 __attribute__((ext_vector_type(4)));
typedef int i32x4 __attribute__((ext_vector_type(4)));

__device__ inline u16 f2bf(float f) {
    union { float f; unsigned int u; } v; v.f = f;
    unsigned int r = v.u + 0x7FFFu + ((v.u >> 16) & 1u);   // round-to-nearest-even
    return (u16)(r >> 16);
}

// Pack 8 fp32 -> 8 bf16 (RNE) via v_cvt_pk_bf16_f32: 4 instrs instead of ~32.
__device__ inline bf16x8 cvt8(const float4& a, const float4& b) {
    union { unsigned int u[4]; bf16x8 v; } r;
    asm("v_cvt_pk_bf16_f32 %0, %1, %2" : "=v"(r.u[0]) : "v"(a.x), "v"(a.y));
    asm("v_cvt_pk_bf16_f32 %0, %1, %2" : "=v"(r.u[1]) : "v"(a.z), "v"(a.w));
    asm("v_cvt_pk_bf16_f32 %0, %1, %2" : "=v"(r.u[2]) : "v"(b.x), "v"(b.y));
    asm("v_cvt_pk_bf16_f32 %0, %1, %2" : "=v"(r.u[3]) : "v"(b.z), "v"(b.w));
    return r.v;
}

__device__ inline float ssq8(const float4& a, const float4& b) {
    return a.x*a.x + a.y*a.y + a.z*a.z + a.w*a.w
         + b.x*b.x + b.y*b.y + b.z*b.z + b.w*b.w;
}

// Fragment-order storage: per (row16-tile, k32-tile) store 64 chunks of 8 bf16.
// chunk slot = quad*16 + (row&15) = lane; matches MFMA A/B layout
// (m|n = lane&15, k = (lane>>4)*8 + j). Tile = 512 u16 = 1 KB.

// ---------------------------------------------------------------------------
// Transpose + convert into fragment order; optionally accumulate column
// sum-of-squares partials into gpart[(r0/64)*N + col] (one write per col/tile,
// no atomics; gpart layout [R/64][C]).
// ---------------------------------------------------------------------------
__device__ inline void transconv_frag(const float* __restrict__ in,
                                      u16* __restrict__ out, int R, int C,
                                      int r0, int c0, int t, float (*tile)[69],
                                      float* __restrict__ gpart) {
    const int lr = t >> 2, lq = t & 3;
    #pragma unroll
    for (int j = 0; j < 4; ++j) {
        float4 v = *(const float4*)(in + (size_t)(r0 + lr) * C + c0 + lq * 16 + j * 4);
        *(float4*)&tile[lr][lq * 16 + j * 4] = v;
    }
    __syncthreads();
    const int oc = t >> 2, oq = t & 3;
    const int row = c0 + oc;
    const int ktiles = R >> 5;
    float ss = 0.f;
    #pragma unroll
    for (int h = 0; h < 2; ++h) {
        const int k0 = r0 + oq * 16 + h * 8;
        const int kt = k0 >> 5, quad = (k0 >> 3) & 3;
        __align__(16) u16 tmp[8];
        #pragma unroll
        for (int e = 0; e < 8; ++e) {
            const float g = tile[oq * 16 + h * 8 + e][oc];
            ss += g * g;
            tmp[e] = f2bf(g);
        }
        const size_t off = ((size_t)((row >> 4) * ktiles + kt)) * 512
                         + (quad * 16 + (row & 15)) * 8;
        *(int4*)(out + off) = *(const int4*)tmp;
    }
    if (gpart) {
        // threads t = oc*4 + oq: reduce over oq (lanes differ in low 2 bits)
        ss += __shfl_xor(ss, 1);
        ss += __shfl_xor(ss, 2);
        if (oq == 0) gpart[(r0 >> 6) * C + row] = ss;
    }
}

// ---------------------------------------------------------------------------
// Prep (G and W only; X is consumed fp32-direct by phi now). 256 blocks:
//   [0,128):   G [I][N] -> GT frag + gsq partials [4][N]
//   [128,256): W [N][O] -> WT frag
// ---------------------------------------------------------------------------
__global__ __launch_bounds__(256) void prep_kernel(
    const float* __restrict__ G_re, const float* __restrict__ G_im,
    const float* __restrict__ W_re, const float* __restrict__ W_im,
    u16* __restrict__ GTfr, u16* __restrict__ GTfi,
    u16* __restrict__ WTfr, u16* __restrict__ WTfi,
    float* __restrict__ gsq_re_part, float* __restrict__ gsq_im_part)
{
    __shared__ float smem[64][69];
    const int blk = blockIdx.x, t = threadIdx.x;

    if (blk < 128) {
        const int comp = blk >> 6, rem = blk & 63;
        const int rt = rem >> 4, ct = rem & 15;   // 4 i-tiles x 16 n-tiles
        transconv_frag(comp ? G_im : G_re, comp ? GTfi : GTfr,
                       I_, N_, rt * 64, ct * 64, t, smem,
                       comp ? gsq_im_part : gsq_re_part);
    } else {
        const int local = blk - 128;
        const int comp = local >> 6, rem = local & 63;
        const int rt = rem >> 2, ct = rem & 3;    // 16 n-tiles x 4 o-tiles
        transconv_frag(comp ? W_im : W_re, comp ? WTfi : WTfr,
                       N_, O_, rt * 64, ct * 64, t, smem, (float*)0);
    }
}

// ---------------------------------------------------------------------------
// phi GEMM (comp per blockIdx.z): C = X @ G^T (K=256). A-operand read directly
// from fp32 X with inline v_cvt_pk_bf16_f32 (xsq accumulated in-register);
// B-operand frag-direct global loads with register prefetch (no LDS in
// K-loop). Tile 64x64, 4 waves 2x2. Grid (16,16,2) = 512.
// Epilogue -> frag-order P via 8 KB LDS + b128 stores.
// ---------------------------------------------------------------------------
__global__ __launch_bounds__(256) void phi_mfma(
    const float* __restrict__ x_re, const float* __restrict__ x_im,
    const u16* __restrict__ GTfr, const u16* __restrict__ GTfi,
    const float* __restrict__ gsq_re_part, const float* __restrict__ gsq_im_part,
    const float* __restrict__ s_re, const float* __restrict__ s_im,
    u16* __restrict__ Pfr, u16* __restrict__ Pfi)
{
    __shared__ u16 pbuf[8 * 512];
    const int z = blockIdx.z;
    const float* Xsrc = z ? x_im : x_re;
    const u16* GTf = z ? GTfi : GTfr;
    const float* gp = z ? gsq_im_part : gsq_re_part;
    const float* s  = z ? s_im : s_re;
    u16* Pf = z ? Pfi : Pfr;

    const int t = threadIdx.x;
    const int w = t >> 6, lane = t & 63;
    const int quad = lane >> 4, l16 = lane & 15;
    const int mw = (w >> 1) * 32, nw = (w & 1) * 32;
    const int m0 = blockIdx.y * 64, n0 = blockIdx.x * 64;
    const int nt0 = blockIdx.x * 4 + (nw >> 4);

    // A: fp32 rows of X (two 16-row tiles per wave), inline convert.
    const float* xr0 = Xsrc + (size_t)(m0 + mw + l16) * I_ + quad * 8;
    const float* xr1 = xr0 + (size_t)16 * I_;
    // B: fragment-order GT tiles.
    const u16* Bb = GTf + lane * 8;
    const size_t b0o = (size_t)(nt0 * 8) * 512;
    const size_t b1o = (size_t)((nt0 + 1) * 8) * 512;

    float4 cA00 = *(const float4*)(xr0);
    float4 cA01 = *(const float4*)(xr0 + 4);
    float4 cA10 = *(const float4*)(xr1);
    float4 cA11 = *(const float4*)(xr1 + 4);
    bf16x8 cB0 = *(const bf16x8*)(Bb + b0o);
    bf16x8 cB1 = *(const bf16x8*)(Bb + b1o);

    f32x4 acc[2][2] = {};
    float ss0 = 0.f, ss1 = 0.f;
    #pragma unroll
    for (int kt = 0; kt < 8; ++kt) {
        float4 nA00, nA01, nA10, nA11;
        bf16x8 nB0, nB1;
        if (kt < 7) {
            nA00 = *(const float4*)(xr0 + (kt + 1) * 32);
            nA01 = *(const float4*)(xr0 + (kt + 1) * 32 + 4);
            nA10 = *(const float4*)(xr1 + (kt + 1) * 32);
            nA11 = *(const float4*)(xr1 + (kt + 1) * 32 + 4);
            const size_t ko = (size_t)(kt + 1) * 512;
            nB0 = *(const bf16x8*)(Bb + b0o + ko);
            nB1 = *(const bf16x8*)(Bb + b1o + ko);
        }
        bf16x8 fA0 = cvt8(cA00, cA01);
        bf16x8 fA1 = cvt8(cA10, cA11);
        ss0 += ssq8(cA00, cA01);
        ss1 += ssq8(cA10, cA11);
        acc[0][0] = __builtin_amdgcn_mfma_f32_16x16x32_bf16(fA0, cB0, acc[0][0], 0, 0, 0);
        acc[0][1] = __builtin_amdgcn_mfma_f32_16x16x32_bf16(fA0, cB1, acc[0][1], 0, 0, 0);
        acc[1][0] = __builtin_amdgcn_mfma_f32_16x16x32_bf16(fA1, cB0, acc[1][0], 0, 0, 0);
        acc[1][1] = __builtin_amdgcn_mfma_f32_16x16x32_bf16(fA1, cB1, acc[1][1], 0, 0, 0);
        cA00 = nA00; cA01 = nA01; cA10 = nA10; cA11 = nA11;
        cB0 = nB0; cB1 = nB1;
    }
    // xsq[row]: lane l16 holds the partial over k = quad*8 + kt*32 slices;
    // reduce across the 4 quads -> every lane holds row (l16)'s full sum.
    ss0 += __shfl_xor(ss0, 16); ss0 += __shfl_xor(ss0, 32);
    ss1 += __shfl_xor(ss1, 16); ss1 += __shfl_xor(ss1, 32);

    // Epilogue into LDS in fragment order. C/D: col = lane&15, row = quad*4+r.
    #pragma unroll
    for (int mt = 0; mt < 2; ++mt)
        #pragma unroll
        for (int nt = 0; nt < 2; ++nt) {
            const int col = nw + nt * 16 + l16;
            const int gn = n0 + col;
            const float gq = gp[gn] + gp[N_ + gn] + gp[2 * N_ + gn] + gp[3 * N_ + gn];
            const float inv_s = 1.0f / fmaxf(s[gn], EPSV);
            #pragma unroll
            for (int r = 0; r < 4; ++r) {
                const int row = mw + mt * 16 + quad * 4 + r;
                const float xq = __shfl(mt ? ss1 : ss0, quad * 4 + r);
                const float v = xq - 2.0f * acc[mt][nt][r] + gq;
                const u16 p = f2bf(__expf(-v * inv_s));
                const int lt = (row >> 4) * 2 + (col >> 5);
                pbuf[lt * 512 + (((col >> 3) & 3) * 16 + (row & 15)) * 8 + (col & 7)] = p;
            }
        }
    __syncthreads();

    const int lt = t >> 5, s32 = t & 31;
    const int mt_g = blockIdx.y * 4 + (lt >> 1);
    const int kt_g = blockIdx.x * 2 + (lt & 1);
    const u16* src = pbuf + lt * 512 + s32 * 16;
    u16* dst = Pf + (size_t)(mt_g * 32 + kt_g) * 512 + s32 * 16;
    *(int4*)dst = *(const int4*)src;
    *((int4*)dst + 1) = *((const int4*)src + 1);
}

// ---------------------------------------------------------------------------
// Complex GEMM, frag-direct, no atomics. Grid (8, 64) = 512 blocks
// (2 blocks/CU): each block 16(b) x 32(o); 4 waves each reduce a K-quarter
// (256) with 1x2 complex fragments + register prefetch; LDS cross-wave
// reduce + bias + coalesced float4 stores.
// ---------------------------------------------------------------------------
__global__ __launch_bounds__(256) void y_mfma(
    const u16* __restrict__ Pfr, const u16* __restrict__ Pfi,
    const u16* __restrict__ WTfr, const u16* __restrict__ WTfi,
    const float* __restrict__ b_re, const float* __restrict__ b_im,
    float* __restrict__ out)
{
    __shared__ float red[4][2][16][34];
    const int t = threadIdx.x;
    const int w = t >> 6, lane = t & 63;
    const int quad = lane >> 4, l16 = lane & 15;
    const int pm = blockIdx.y;        // P 16-row tile (32 ktiles)
    const int wo0 = blockIdx.x * 2;   // WT 16-row tiles

    const u16* Ar = Pfr + lane * 8;
    const u16* Ai = Pfi + lane * 8;
    const u16* Br = WTfr + lane * 8;
    const u16* Bi = WTfi + lane * 8;
    const size_t ao = (size_t)(pm * 32 + w * 8) * 512;
    const size_t b0o = (size_t)(wo0 * 32 + w * 8) * 512;
    const size_t b1o = (size_t)((wo0 + 1) * 32 + w * 8) * 512;

    bf16x8 cAr = *(const bf16x8*)(Ar + ao);
    bf16x8 cAi = *(const bf16x8*)(Ai + ao);
    bf16x8 cBr0 = *(const bf16x8*)(Br + b0o);
    bf16x8 cBi0 = *(const bf16x8*)(Bi + b0o);
    bf16x8 cBr1 = *(const bf16x8*)(Br + b1o);
    bf16x8 cBi1 = *(const bf16x8*)(Bi + b1o);

    f32x4 cr[2] = {}, ci[2] = {};
    #pragma unroll
    for (int ks = 0; ks < 8; ++ks) {
        bf16x8 nAr, nAi, nBr0, nBi0, nBr1, nBi1;
        if (ks < 7) {
            const size_t ko = (size_t)(ks + 1) * 512;
            nAr  = *(const bf16x8*)(Ar + ao + ko);
            nAi  = *(const bf16x8*)(Ai + ao + ko);
            nBr0 = *(const bf16x8*)(Br + b0o + ko);
            nBi0 = *(const bf16x8*)(Bi + b0o + ko);
            nBr1 = *(const bf16x8*)(Br + b1o + ko);
            nBi1 = *(const bf16x8*)(Bi + b1o + ko);
        }
        i32x4 tv = (*(const i32x4*)&cAi) ^ 0x80008000;   // negate bf16 pairs
        bf16x8 cAn = *(const bf16x8*)&tv;
        cr[0] = __builtin_amdgcn_mfma_f32_16x16x32_bf16(cAr, cBr0, cr[0], 0, 0, 0);
        cr[0] = __builtin_amdgcn_mfma_f32_16x16x32_bf16(cAn, cBi0, cr[0], 0, 0, 0);
        ci[0] = __builtin_amdgcn_mfma_f32_16x16x32_bf16(cAr, cBi0, ci[0], 0, 0, 0);
        ci[0] = __builtin_amdgcn_mfma_f32_16x16x32_bf16(cAi, cBr0, ci[0], 0, 0, 0);
        cr[1] = __builtin_amdgcn_mfma_f32_16x16x32_bf16(cAr, cBr1, cr[1], 0, 0, 0);
        cr[1] = __builtin_amdgcn_mfma_f32_16x16x32_bf16(cAn, cBi1, cr[1], 0, 0, 0);
        ci[1] = __builtin_amdgcn_mfma_f32_16x16x32_bf16(cAr, cBi1, ci[1], 0, 0, 0);
        ci[1] = __builtin_amdgcn_mfma_f32_16x16x32_bf16(cAi, cBr1, ci[1], 0, 0, 0);
        cAr = nAr; cAi = nAi;
        cBr0 = nBr0; cBi0 = nBi0; cBr1 = nBr1; cBi1 = nBi1;
    }

    // C/D: o_local = nt*16 + l16, b_local = quad*4 + r.
    #pragma unroll
    for (int nt = 0; nt < 2; ++nt) {
        const int o = nt * 16 + l16;
        #pragma unroll
        for (int r = 0; r < 4; ++r) {
            const int b = quad * 4 + r;
            red[w][0][b][o] = cr[nt][r];
            red[w][1][b][o] = ci[nt][r];
        }
    }
    __syncthreads();

    const int b = t >> 4, oq = t & 15;
    const int o = oq * 2;
    const int gb = blockIdx.y * 16 + b;
    const int go = blockIdx.x * 32 + o;
    float r0 = red[0][0][b][o]   + red[1][0][b][o]   + red[2][0][b][o]   + red[3][0][b][o];
    float i0 = red[0][1][b][o]   + red[1][1][b][o]   + red[2][1][b][o]   + red[3][1][b][o];
    float r1 = red[0][0][b][o+1] + red[1][0][b][o+1] + red[2][0][b][o+1] + red[3][0][b][o+1];
    float i1 = red[0][1][b][o+1] + red[1][1][b][o+1] + red[2][1][b][o+1] + red[3][1][b][o+1];
    float4 v;
    v.x = r0 + b_re[go];     v.y = i0 + b_im[go];
    v.z = r1 + b_re[go + 1]; v.w = i1 + b_im[go + 1];
    *(float4*)(out + ((size_t)gb * O_ + go) * 2) = v;
}

extern "C" void kernel_launch(void* const* d_in, const int* in_sizes, int n_in,
                              void* d_out, int out_size, void* d_ws, size_t ws_size,
                              hipStream_t stream) {
    const float* x_re = (const float*)d_in[0];
    const float* x_im = (const float*)d_in[1];
    const float* G_re = (const float*)d_in[2];
    const float* G_im = (const float*)d_in[3];
    const float* s_re = (const float*)d_in[4];
    const float* s_im = (const float*)d_in[5];
    const float* W_re = (const float*)d_in[6];
    const float* W_im = (const float*)d_in[7];
    const float* b_re = (const float*)d_in[8];
    const float* b_im = (const float*)d_in[9];
    float* out = (float*)d_out;

    u16* GTfr = (u16*)d_ws;
    u16* GTfi = GTfr + (size_t)N_ * I_;
    u16* WTfr = GTfi + (size_t)N_ * I_;
    u16* WTfi = WTfr + (size_t)O_ * N_;
    u16* Pfr  = WTfi + (size_t)O_ * N_;
    u16* Pfi  = Pfr  + (size_t)B_ * N_;
    float* gsq_re_part = (float*)(Pfi + (size_t)B_ * N_);   // [4][N_]
    float* gsq_im_part = gsq_re_part + 4 * N_;

    prep_kernel<<<256, 256, 0, stream>>>(
        G_re, G_im, W_re, W_im,
        GTfr, GTfi, WTfr, WTfi,
        gsq_re_part, gsq_im_part);

    phi_mfma<<<dim3(N_ / 64, B_ / 64, 2), 256, 0, stream>>>(
        x_re, x_im, GTfr, GTfi, gsq_re_part, gsq_im_part,
        s_re, s_im, Pfr, Pfi);

    y_mfma<<<dim3(O_ / 32, B_ / 16), 256, 0, stream>>>(
        Pfr, Pfi, WTfr, WTfi, b_re, b_im, out);
}

// Round 3
// 90.948 us; speedup vs baseline: 1.2263x; 1.0367x over previous
//
#include <hip/hip_runtime.h>
#include <math.h>

#define B_ 1024
#define I_ 256
#define N_ 1024
#define O_ 256
#define EPSV 1e-5f

typedef unsigned short u16;
typedef short bf16x8 __attribute__((ext_vector_type(8)));   // 8 bf16 = 4 VGPRs
typedef float f32x4 __attribute__((ext_vector_type(4)));
typedef int i32x4 __attribute__((ext_vector_type(4)));

__device__ inline u16 f2bf(float f) {
    union { float f; unsigned int u; } v; v.f = f;
    unsigned int r = v.u + 0x7FFFu + ((v.u >> 16) & 1u);   // round-to-nearest-even
    return (u16)(r >> 16);
}

// Fragment-order storage: per (row16-tile, k32-tile) store 64 chunks of 8 bf16.
// chunk slot = quad*16 + (row&15) = lane; matches MFMA A/B layout
// (m|n = lane&15, k = (lane>>4)*8 + j). Tile = 512 u16 = 1 KB.

// ---------------------------------------------------------------------------
// Transpose + convert into fragment order; optionally accumulate column
// sum-of-squares partials into gpart[(r0/64)*N + col] (one write per col/tile,
// no atomics; gpart layout [R/64][C]).
// ---------------------------------------------------------------------------
__device__ inline void transconv_frag(const float* __restrict__ in,
                                      u16* __restrict__ out, int R, int C,
                                      int r0, int c0, int t, float (*tile)[69],
                                      float* __restrict__ gpart) {
    const int lr = t >> 2, lq = t & 3;
    #pragma unroll
    for (int j = 0; j < 4; ++j) {
        float4 v = *(const float4*)(in + (size_t)(r0 + lr) * C + c0 + lq * 16 + j * 4);
        *(float4*)&tile[lr][lq * 16 + j * 4] = v;
    }
    __syncthreads();
    const int oc = t >> 2, oq = t & 3;
    const int row = c0 + oc;
    const int ktiles = R >> 5;
    float ss = 0.f;
    #pragma unroll
    for (int h = 0; h < 2; ++h) {
        const int k0 = r0 + oq * 16 + h * 8;
        const int kt = k0 >> 5, quad = (k0 >> 3) & 3;
        __align__(16) u16 tmp[8];
        #pragma unroll
        for (int e = 0; e < 8; ++e) {
            const float g = tile[oq * 16 + h * 8 + e][oc];
            ss += g * g;
            tmp[e] = f2bf(g);
        }
        const size_t off = ((size_t)((row >> 4) * ktiles + kt)) * 512
                         + (quad * 16 + (row & 15)) * 8;
        *(int4*)(out + off) = *(const int4*)tmp;
    }
    if (gpart) {
        // threads t = oc*4 + oq: reduce over oq (lanes differ in low 2 bits)
        ss += __shfl_xor(ss, 1);
        ss += __shfl_xor(ss, 2);
        if (oq == 0) gpart[(r0 >> 6) * C + row] = ss;
    }
}

// ---------------------------------------------------------------------------
// Fused prep, 288 uniform blocks:
//   [0,32):    X fp32 -> frag bf16 + xsq (1 wave per (comp, 16-row tile))
//   [32,160):  G [I][N] -> GT frag + gsq partials [4][N]
//   [160,288): W [N][O] -> WT frag
// ---------------------------------------------------------------------------
__global__ __launch_bounds__(256) void prep_kernel(
    const float* __restrict__ x_re, const float* __restrict__ x_im,
    const float* __restrict__ G_re, const float* __restrict__ G_im,
    const float* __restrict__ W_re, const float* __restrict__ W_im,
    u16* __restrict__ Xfr, u16* __restrict__ Xfi,
    u16* __restrict__ GTfr, u16* __restrict__ GTfi,
    u16* __restrict__ WTfr, u16* __restrict__ WTfi,
    float* __restrict__ xsq_re, float* __restrict__ xsq_im,
    float* __restrict__ gsq_re_part, float* __restrict__ gsq_im_part)
{
    __shared__ float smem[64][69];
    const int blk = blockIdx.x, t = threadIdx.x;

    if (blk < 32) {
        const int unit = blk * 4 + (t >> 6);     // [0,128): comp x 64 m-tiles
        const int comp = unit >> 6, mt = unit & 63;
        const int lane = t & 63;
        const int l16 = lane & 15, quad = lane >> 4;
        const float* src = (comp ? x_im : x_re)
                         + (size_t)(mt * 16 + l16) * I_ + quad * 8;
        u16* dstbase = (comp ? Xfi : Xfr) + (size_t)(mt * 8) * 512 + lane * 8;
        float ssum = 0.f;
        #pragma unroll
        for (int kt = 0; kt < 8; ++kt) {
            float4 a0 = *(const float4*)(src + kt * 32);
            float4 a1 = *(const float4*)(src + kt * 32 + 4);
            ssum += a0.x*a0.x + a0.y*a0.y + a0.z*a0.z + a0.w*a0.w
                  + a1.x*a1.x + a1.y*a1.y + a1.z*a1.z + a1.w*a1.w;
            __align__(16) u16 tmp[8];
            tmp[0] = f2bf(a0.x); tmp[1] = f2bf(a0.y);
            tmp[2] = f2bf(a0.z); tmp[3] = f2bf(a0.w);
            tmp[4] = f2bf(a1.x); tmp[5] = f2bf(a1.y);
            tmp[6] = f2bf(a1.z); tmp[7] = f2bf(a1.w);
            *(int4*)(dstbase + (size_t)kt * 512) = *(const int4*)tmp;
        }
        // row r partials live in lanes r, r+16, r+32, r+48
        ssum += __shfl_xor(ssum, 16);
        ssum += __shfl_xor(ssum, 32);
        if (lane < 16) {
            float* xsq = comp ? xsq_im : xsq_re;
            xsq[mt * 16 + lane] = ssum;
        }
    } else if (blk < 160) {
        const int local = blk - 32;
        const int comp = local >> 6, rem = local & 63;
        const int rt = rem >> 4, ct = rem & 15;   // 4 i-tiles x 16 n-tiles
        transconv_frag(comp ? G_im : G_re, comp ? GTfi : GTfr,
                       I_, N_, rt * 64, ct * 64, t, smem,
                       comp ? gsq_im_part : gsq_re_part);
    } else {
        const int local = blk - 160;
        const int comp = local >> 6, rem = local & 63;
        const int rt = rem >> 2, ct = rem & 3;    // 16 n-tiles x 4 o-tiles
        transconv_frag(comp ? W_im : W_re, comp ? WTfi : WTfr,
                       N_, O_, rt * 64, ct * 64, t, smem, (float*)0);
    }
}

// ---------------------------------------------------------------------------
// phi GEMM (comp per blockIdx.z): C = X @ G^T (K=256), frag-direct loads with
// register prefetch (no LDS in K-loop). Tile 64x64, 4 waves 2x2.
// Grid (16,16,2) = 512. Epilogue -> frag-order P via 8 KB LDS + b128 stores.
// gsq comes as 4 partials [4][N].
// ---------------------------------------------------------------------------
__global__ __launch_bounds__(256) void phi_mfma(
    const u16* __restrict__ Xfr, const u16* __restrict__ Xfi,
    const u16* __restrict__ GTfr, const u16* __restrict__ GTfi,
    const float* __restrict__ xsq_re, const float* __restrict__ xsq_im,
    const float* __restrict__ gsq_re_part, const float* __restrict__ gsq_im_part,
    const float* __restrict__ s_re, const float* __restrict__ s_im,
    u16* __restrict__ Pfr, u16* __restrict__ Pfi)
{
    __shared__ u16 pbuf[8 * 512];
    const int z = blockIdx.z;
    const u16* Xf  = z ? Xfi : Xfr;
    const u16* GTf = z ? GTfi : GTfr;
    const float* xsq = z ? xsq_im : xsq_re;
    const float* gp  = z ? gsq_im_part : gsq_re_part;
    const float* s   = z ? s_im : s_re;
    u16* Pf = z ? Pfi : Pfr;

    const int t = threadIdx.x;
    const int w = t >> 6, lane = t & 63;
    const int quad = lane >> 4, l16 = lane & 15;
    const int mw = (w >> 1) * 32, nw = (w & 1) * 32;
    const int mt0 = blockIdx.y * 4 + (mw >> 4);
    const int nt0 = blockIdx.x * 4 + (nw >> 4);

    const u16* Ab = Xf  + lane * 8;
    const u16* Bb = GTf + lane * 8;
    const size_t a0o = (size_t)(mt0 * 8) * 512;
    const size_t a1o = (size_t)((mt0 + 1) * 8) * 512;
    const size_t b0o = (size_t)(nt0 * 8) * 512;
    const size_t b1o = (size_t)((nt0 + 1) * 8) * 512;

    bf16x8 cA0 = *(const bf16x8*)(Ab + a0o);
    bf16x8 cA1 = *(const bf16x8*)(Ab + a1o);
    bf16x8 cB0 = *(const bf16x8*)(Bb + b0o);
    bf16x8 cB1 = *(const bf16x8*)(Bb + b1o);

    f32x4 acc[2][2] = {};
    #pragma unroll
    for (int kt = 0; kt < 8; ++kt) {
        bf16x8 nA0, nA1, nB0, nB1;
        if (kt < 7) {
            const size_t ko = (size_t)(kt + 1) * 512;
            nA0 = *(const bf16x8*)(Ab + a0o + ko);
            nA1 = *(const bf16x8*)(Ab + a1o + ko);
            nB0 = *(const bf16x8*)(Bb + b0o + ko);
            nB1 = *(const bf16x8*)(Bb + b1o + ko);
        }
        acc[0][0] = __builtin_amdgcn_mfma_f32_16x16x32_bf16(cA0, cB0, acc[0][0], 0, 0, 0);
        acc[0][1] = __builtin_amdgcn_mfma_f32_16x16x32_bf16(cA0, cB1, acc[0][1], 0, 0, 0);
        acc[1][0] = __builtin_amdgcn_mfma_f32_16x16x32_bf16(cA1, cB0, acc[1][0], 0, 0, 0);
        acc[1][1] = __builtin_amdgcn_mfma_f32_16x16x32_bf16(cA1, cB1, acc[1][1], 0, 0, 0);
        cA0 = nA0; cA1 = nA1; cB0 = nB0; cB1 = nB1;
    }

    // Epilogue into LDS in fragment order. C/D: col = lane&15, row = quad*4+r.
    const int m0 = blockIdx.y * 64, n0 = blockIdx.x * 64;
    #pragma unroll
    for (int mt = 0; mt < 2; ++mt)
        #pragma unroll
        for (int nt = 0; nt < 2; ++nt) {
            const int col = nw + nt * 16 + l16;
            const int gn = n0 + col;
            const float gq = gp[gn] + gp[N_ + gn] + gp[2 * N_ + gn] + gp[3 * N_ + gn];
            const float inv_s = 1.0f / fmaxf(s[gn], EPSV);
            #pragma unroll
            for (int r = 0; r < 4; ++r) {
                const int row = mw + mt * 16 + quad * 4 + r;
                const float v = xsq[m0 + row] - 2.0f * acc[mt][nt][r] + gq;
                const u16 p = f2bf(__expf(-v * inv_s));
                const int lt = (row >> 4) * 2 + (col >> 5);
                pbuf[lt * 512 + (((col >> 3) & 3) * 16 + (row & 15)) * 8 + (col & 7)] = p;
            }
        }
    __syncthreads();

    const int lt = t >> 5, s32 = t & 31;
    const int mt_g = blockIdx.y * 4 + (lt >> 1);
    const int kt_g = blockIdx.x * 2 + (lt & 1);
    const u16* src = pbuf + lt * 512 + s32 * 16;
    u16* dst = Pf + (size_t)(mt_g * 32 + kt_g) * 512 + s32 * 16;
    *(int4*)dst = *(const int4*)src;
    *((int4*)dst + 1) = *((const int4*)src + 1);
}

// ---------------------------------------------------------------------------
// Complex GEMM, frag-direct, no atomics. Grid (8, 64) = 512 blocks
// (2 blocks/CU): each block 16(b) x 32(o); 4 waves each reduce a K-quarter
// (256) with 1x2 complex fragments + register prefetch; LDS cross-wave
// reduce + bias + coalesced float4 stores.
// ---------------------------------------------------------------------------
__global__ __launch_bounds__(256) void y_mfma(
    const u16* __restrict__ Pfr, const u16* __restrict__ Pfi,
    const u16* __restrict__ WTfr, const u16* __restrict__ WTfi,
    const float* __restrict__ b_re, const float* __restrict__ b_im,
    float* __restrict__ out)
{
    __shared__ float red[4][2][16][34];
    const int t = threadIdx.x;
    const int w = t >> 6, lane = t & 63;
    const int quad = lane >> 4, l16 = lane & 15;
    const int pm = blockIdx.y;        // P 16-row tile (32 ktiles)
    const int wo0 = blockIdx.x * 2;   // WT 16-row tiles

    const u16* Ar = Pfr + lane * 8;
    const u16* Ai = Pfi + lane * 8;
    const u16* Br = WTfr + lane * 8;
    const u16* Bi = WTfi + lane * 8;
    const size_t ao = (size_t)(pm * 32 + w * 8) * 512;
    const size_t b0o = (size_t)(wo0 * 32 + w * 8) * 512;
    const size_t b1o = (size_t)((wo0 + 1) * 32 + w * 8) * 512;

    bf16x8 cAr = *(const bf16x8*)(Ar + ao);
    bf16x8 cAi = *(const bf16x8*)(Ai + ao);
    bf16x8 cBr0 = *(const bf16x8*)(Br + b0o);
    bf16x8 cBi0 = *(const bf16x8*)(Bi + b0o);
    bf16x8 cBr1 = *(const bf16x8*)(Br + b1o);
    bf16x8 cBi1 = *(const bf16x8*)(Bi + b1o);

    f32x4 cr[2] = {}, ci[2] = {};
    #pragma unroll
    for (int ks = 0; ks < 8; ++ks) {
        bf16x8 nAr, nAi, nBr0, nBi0, nBr1, nBi1;
        if (ks < 7) {
            const size_t ko = (size_t)(ks + 1) * 512;
            nAr  = *(const bf16x8*)(Ar + ao + ko);
            nAi  = *(const bf16x8*)(Ai + ao + ko);
            nBr0 = *(const bf16x8*)(Br + b0o + ko);
            nBi0 = *(const bf16x8*)(Bi + b0o + ko);
            nBr1 = *(const bf16x8*)(Br + b1o + ko);
            nBi1 = *(const bf16x8*)(Bi + b1o + ko);
        }
        i32x4 tv = (*(const i32x4*)&cAi) ^ 0x80008000;   // negate bf16 pairs
        bf16x8 cAn = *(const bf16x8*)&tv;
        cr[0] = __builtin_amdgcn_mfma_f32_16x16x32_bf16(cAr, cBr0, cr[0], 0, 0, 0);
        cr[0] = __builtin_amdgcn_mfma_f32_16x16x32_bf16(cAn, cBi0, cr[0], 0, 0, 0);
        ci[0] = __builtin_amdgcn_mfma_f32_16x16x32_bf16(cAr, cBi0, ci[0], 0, 0, 0);
        ci[0] = __builtin_amdgcn_mfma_f32_16x16x32_bf16(cAi, cBr0, ci[0], 0, 0, 0);
        cr[1] = __builtin_amdgcn_mfma_f32_16x16x32_bf16(cAr, cBr1, cr[1], 0, 0, 0);
        cr[1] = __builtin_amdgcn_mfma_f32_16x16x32_bf16(cAn, cBi1, cr[1], 0, 0, 0);
        ci[1] = __builtin_amdgcn_mfma_f32_16x16x32_bf16(cAr, cBi1, ci[1], 0, 0, 0);
        ci[1] = __builtin_amdgcn_mfma_f32_16x16x32_bf16(cAi, cBr1, ci[1], 0, 0, 0);
        cAr = nAr; cAi = nAi;
        cBr0 = nBr0; cBi0 = nBi0; cBr1 = nBr1; cBi1 = nBi1;
    }

    // C/D: o_local = nt*16 + l16, b_local = quad*4 + r.
    #pragma unroll
    for (int nt = 0; nt < 2; ++nt) {
        const int o = nt * 16 + l16;
        #pragma unroll
        for (int r = 0; r < 4; ++r) {
            const int b = quad * 4 + r;
            red[w][0][b][o] = cr[nt][r];
            red[w][1][b][o] = ci[nt][r];
        }
    }
    __syncthreads();

    const int b = t >> 4, oq = t & 15;
    const int o = oq * 2;
    const int gb = blockIdx.y * 16 + b;
    const int go = blockIdx.x * 32 + o;
    float r0 = red[0][0][b][o]   + red[1][0][b][o]   + red[2][0][b][o]   + red[3][0][b][o];
    float i0 = red[0][1][b][o]   + red[1][1][b][o]   + red[2][1][b][o]   + red[3][1][b][o];
    float r1 = red[0][0][b][o+1] + red[1][0][b][o+1] + red[2][0][b][o+1] + red[3][0][b][o+1];
    float i1 = red[0][1][b][o+1] + red[1][1][b][o+1] + red[2][1][b][o+1] + red[3][1][b][o+1];
    float4 v;
    v.x = r0 + b_re[go];     v.y = i0 + b_im[go];
    v.z = r1 + b_re[go + 1]; v.w = i1 + b_im[go + 1];
    *(float4*)(out + ((size_t)gb * O_ + go) * 2) = v;
}

extern "C" void kernel_launch(void* const* d_in, const int* in_sizes, int n_in,
                              void* d_out, int out_size, void* d_ws, size_t ws_size,
                              hipStream_t stream) {
    const float* x_re = (const float*)d_in[0];
    const float* x_im = (const float*)d_in[1];
    const float* G_re = (const float*)d_in[2];
    const float* G_im = (const float*)d_in[3];
    const float* s_re = (const float*)d_in[4];
    const float* s_im = (const float*)d_in[5];
    const float* W_re = (const float*)d_in[6];
    const float* W_im = (const float*)d_in[7];
    const float* b_re = (const float*)d_in[8];
    const float* b_im = (const float*)d_in[9];
    float* out = (float*)d_out;

    u16* Xfr  = (u16*)d_ws;
    u16* Xfi  = Xfr  + (size_t)B_ * I_;
    u16* GTfr = Xfi  + (size_t)B_ * I_;
    u16* GTfi = GTfr + (size_t)N_ * I_;
    u16* WTfr = GTfi + (size_t)N_ * I_;
    u16* WTfi = WTfr + (size_t)O_ * N_;
    u16* Pfr  = WTfi + (size_t)O_ * N_;
    u16* Pfi  = Pfr  + (size_t)B_ * N_;
    float* xsq_re = (float*)(Pfi + (size_t)B_ * N_);
    float* xsq_im = xsq_re + B_;
    float* gsq_re_part = xsq_im + B_;        // [4][N_]
    float* gsq_im_part = gsq_re_part + 4 * N_;

    prep_kernel<<<288, 256, 0, stream>>>(
        x_re, x_im, G_re, G_im, W_re, W_im,
        Xfr, Xfi, GTfr, GTfi, WTfr, WTfi,
        xsq_re, xsq_im, gsq_re_part, gsq_im_part);

    phi_mfma<<<dim3(N_ / 64, B_ / 64, 2), 256, 0, stream>>>(
        Xfr, Xfi, GTfr, GTfi, xsq_re, xsq_im, gsq_re_part, gsq_im_part,
        s_re, s_im, Pfr, Pfi);

    y_mfma<<<dim3(O_ / 32, B_ / 16), 256, 0, stream>>>(
        Pfr, Pfi, WTfr, WTfi, b_re, b_im, out);
}